// Round 20
// baseline (144.432 us; speedup 1.0000x reference)
//
#include <hip/hip_runtime.h>
#include <math.h>

#define NB 4
#define CC 256
#define CO 32
#define NN 4096
#define MU 320   // concat projection rows: 32 q + 32 k + 256 v
#define LOG2E 1.44269504088896f

typedef __attribute__((ext_vector_type(4))) float f4;
typedef __attribute__((ext_vector_type(8))) short s8;          // 8 bf16 MFMA frag
typedef __attribute__((ext_vector_type(8))) unsigned short us8;
typedef __attribute__((ext_vector_type(2))) unsigned int u2;
typedef __attribute__((ext_vector_type(4))) unsigned int u4i;

// fp32 -> bf16 (RNE), scalar fallback
__device__ __forceinline__ unsigned short f2bf(float f) {
    unsigned int u = __float_as_uint(f);
    u = (u + 0x7FFFu + ((u >> 16) & 1u)) >> 16;
    return (unsigned short)u;
}
// HW packed convert: dst = {bf16(lo), bf16(hi)}
__device__ __forceinline__ unsigned int cvtpk(float lo, float hi) {
    unsigned int r;
    asm("v_cvt_pk_bf16_f32 %0, %1, %2" : "=v"(r) : "v"(lo), "v"(hi));
    return r;
}

union s8u4 { s8 s; u4i u; };

// ---------------------------------------------------------------------------
// prepw: grid 80. Wb[320][256] bf16, fb[320] f32.  (passing, unchanged)
// ---------------------------------------------------------------------------
__global__ __launch_bounds__(256) void prepw_kernel(
    const float* __restrict__ Wq, const float* __restrict__ bq,
    const float* __restrict__ Wk, const float* __restrict__ bk,
    const float* __restrict__ Wv, const float* __restrict__ bv,
    unsigned short* __restrict__ Wb, float* __restrict__ fb)
{
    const int t = threadIdx.x;
    #pragma unroll
    for (int i = 0; i < 4; ++i) {
        const int e = blockIdx.x * 1024 + i * 256 + t;
        const int u = e >> 8, c = e & 255;
        float val = (u < 32) ? Wq[u * 256 + c]
                  : (u < 64) ? Wk[(u - 32) * 256 + c]
                             : Wv[(u - 64) * 256 + c];
        Wb[e] = f2bf(val);
    }
    if (blockIdx.x == 0) {
        for (int u = t; u < MU; u += 256)
            fb[u] = (u < 32) ? bq[u] : (u < 64) ? bk[u - 32] : bv[u - 64];
    }
}

// ---------------------------------------------------------------------------
// projf: fused transpose + MFMA projection (passing, unchanged).
// ---------------------------------------------------------------------------
__global__ __launch_bounds__(256) void projf_kernel(
    const float* __restrict__ x, const unsigned short* __restrict__ Wb,
    const float* __restrict__ fb,
    unsigned short* __restrict__ qb, unsigned short* __restrict__ kb,
    unsigned short* __restrict__ vtb)
{
    __shared__ float xl[32][260];

    const int t   = threadIdx.x;
    const int b   = blockIdx.x >> 7;
    const int nbl = blockIdx.x & 127;
    const int n0  = nbl * 32;

    {
        const int nl = t & 7;
        const int c8 = t >> 3;
        #pragma unroll
        for (int pass = 0; pass < 8; ++pass) {
            const int c = c8 + pass * 32;
            f4 xv = *reinterpret_cast<const f4*>(x + ((size_t)(b * CC + c)) * NN + n0 + nl * 4);
            #pragma unroll
            for (int j = 0; j < 4; ++j) xl[nl * 4 + j][c] = xv[j];
        }
    }
    __syncthreads();

    const int w    = t >> 6;
    const int l    = t & 63;
    const int l15  = l & 15;
    const int g4   = l >> 4;
    const int nw   = w & 1;
    const int uw   = w >> 1;
    const int nloc = nw * 16 + l15;
    const int n    = n0 + nloc;

    s8 bfr[8];
    #pragma unroll
    for (int kk = 0; kk < 8; ++kk) {
        f4 a  = *reinterpret_cast<const f4*>(&xl[nloc][kk * 32 + g4 * 8]);
        f4 c2 = *reinterpret_cast<const f4*>(&xl[nloc][kk * 32 + g4 * 8 + 4]);
        s8u4 tmp;
        tmp.u = (u4i){ cvtpk(a[0], a[1]), cvtpk(a[2], a[3]),
                       cvtpk(c2[0], c2[1]), cvtpk(c2[2], c2[3]) };
        bfr[kk] = tmp.s;
    }

    const f4 z = {0.f, 0.f, 0.f, 0.f};
    unsigned short* qrow = qb + ((size_t)(b * NN + n)) * CO;
    unsigned short* krow = kb + ((size_t)(b * NN + n)) * CO;

    #pragma unroll
    for (int i = 0; i < 10; ++i) {
        const int u0 = (uw * 10 + i) * 16;
        f4 acc = z;
        #pragma unroll
        for (int kk = 0; kk < 8; ++kk) {
            s8 af = *reinterpret_cast<const s8*>(Wb + (size_t)(u0 + l15) * CC + kk * 32 + g4 * 8);
            acc = __builtin_amdgcn_mfma_f32_16x16x32_bf16(af, bfr[kk], acc, 0, 0, 0);
        }
        f4 bias4 = *reinterpret_cast<const f4*>(fb + u0 + g4 * 4);
        if (u0 < 32) {
            u2 pw = { cvtpk((acc[0] + bias4[0]) * LOG2E, (acc[1] + bias4[1]) * LOG2E),
                      cvtpk((acc[2] + bias4[2]) * LOG2E, (acc[3] + bias4[3]) * LOG2E) };
            *reinterpret_cast<u2*>(qrow + u0 + g4 * 4) = pw;
        } else if (u0 < 64) {
            u2 pw = { cvtpk(acc[0] + bias4[0], acc[1] + bias4[1]),
                      cvtpk(acc[2] + bias4[2], acc[3] + bias4[3]) };
            *reinterpret_cast<u2*>(krow + (u0 - 32) + g4 * 4) = pw;
        } else {
            const int cbase = u0 - 64 + g4 * 4;
            #pragma unroll
            for (int r = 0; r < 4; ++r)
                vtb[((size_t)(b * CC + cbase + r)) * NN + n] = f2bf(acc[r] + bias4[r]);
        }
    }
}

// ---------------------------------------------------------------------------
// colstats: civ + scaled V in MFMA fragment order (vfr). (passing, unchanged)
// ---------------------------------------------------------------------------
__global__ __launch_bounds__(256) void colstats_kernel(
    const unsigned short* __restrict__ qb, const unsigned short* __restrict__ kb,
    const unsigned short* __restrict__ vtb, unsigned short* __restrict__ vfr)
{
    __shared__ float red[4][16];
    __shared__ float civl[16];

    const int t   = threadIdx.x;
    const int b   = blockIdx.x >> 8;
    const int mb  = blockIdx.x & 255;
    const int l   = t & 63;
    const int w   = t >> 6;
    const int l15 = l & 15;
    const int g4  = l >> 4;
    const int m   = mb * 16 + l15;

    const unsigned short* qbB = qb + (size_t)b * NN * CO;
    s8 kfrag = *reinterpret_cast<const s8*>(kb + ((size_t)b * NN + m) * CO + g4 * 8);

    const f4 z = {0.f, 0.f, 0.f, 0.f};
    float ssum = 0.f;

    const int nbeg = w * 1024, nend = nbeg + 1024;
    for (int n0 = nbeg; n0 < nend; n0 += 32) {
        s8 a0 = *reinterpret_cast<const s8*>(qbB + (size_t)(n0 + l15) * CO + g4 * 8);
        s8 a1 = *reinterpret_cast<const s8*>(qbB + (size_t)(n0 + 16 + l15) * CO + g4 * 8);
        f4 d0 = __builtin_amdgcn_mfma_f32_16x16x32_bf16(a0, kfrag, z, 0, 0, 0);
        f4 d1 = __builtin_amdgcn_mfma_f32_16x16x32_bf16(a1, kfrag, z, 0, 0, 0);
        #pragma unroll
        for (int r = 0; r < 4; ++r) ssum += exp2f(d0[r]) + exp2f(d1[r]);
    }

    ssum += __shfl_xor(ssum, 16);
    ssum += __shfl_xor(ssum, 32);
    if (l < 16) red[w][l15] = ssum;
    __syncthreads();
    if (w == 0 && l < 16)
        civl[l15] = 1.0f / (red[0][l15] + red[1][l15] + red[2][l15] + red[3][l15]);
    __syncthreads();

    const int mt   = mb >> 2;
    const int ksl  = (mb >> 1) & 1;
    const int g4b  = (mb & 1) * 2;
    const int cg   = t >> 4;
    const int l15v = t & 15;
    const unsigned short* vp = vtb + ((size_t)(b * CC + t)) * NN + mb * 16;
    unsigned short* dst = vfr + (size_t)b * 1048576
                        + (((mt * 16 + cg) * 2 + ksl) << 9)
                        + (g4b * 16 + l15v) * 8;
    #pragma unroll
    for (int i = 0; i < 2; ++i) {
        us8 vv = *reinterpret_cast<const us8*>(vp + i * 8);
        u4i o;
        #pragma unroll
        for (int e2 = 0; e2 < 4; ++e2) {
            float f0 = __uint_as_float((unsigned int)vv[2 * e2]     << 16) * civl[i * 8 + 2 * e2];
            float f1 = __uint_as_float((unsigned int)vv[2 * e2 + 1] << 16) * civl[i * 8 + 2 * e2 + 1];
            o[e2] = cvtpk(f0, f1);
        }
        *reinterpret_cast<u4i*>(dst + i * 128) = o;
    }
}

// ---------------------------------------------------------------------------
// attn: FULLY WAVE-INDEPENDENT, ZERO BARRIERS.
// Wave owns out[32n x 64c]: 2048 waves = 256 blocks x 8 waves (1 block/CU).
// Per 64m tile: S = 8 swapped MFMA (own n-rows; 4x S duplication accepted);
// P transposed through PRIVATE per-wave LDS [32 rows x 144B pad] (conflict-
// free, intra-wave s_waitcnt only); PV = 16 MFMA with A=V' frags straight
// from vfr (same lane mapping as verified B-usage), D[c][n] -> f4 out stores.
// K/V register double-buffered one tile ahead.
// ---------------------------------------------------------------------------
__global__ __launch_bounds__(512, 2) void attn_kernel(
    const unsigned short* __restrict__ qb, const unsigned short* __restrict__ kb,
    const unsigned short* __restrict__ vfr, float* __restrict__ out)
{
    __shared__ __align__(16) char plds[8][32 * 144];   // private per-wave P buffer

    const int t    = threadIdx.x;
    const int w    = t >> 6;
    const int l    = t & 63;
    const int l15  = l & 15;
    const int g4   = l >> 4;
    const int bid  = blockIdx.x;
    const int b    = bid >> 6;
    const int rem  = bid & 63;
    const int chunk = rem * 8 + w;      // 0..511
    const int ch   = chunk & 3;         // c-half (64 c)
    const int nc   = chunk >> 2;        // 0..127
    const int n0   = nc * 32;
    const int c0   = ch * 64;

    const unsigned short* qbB = qb + (size_t)b * NN * CO;
    const unsigned short* kbB = kb + (size_t)b * NN * CO;

    // wave's 32 S-rows as two B-operand frags
    s8 qf0 = *reinterpret_cast<const s8*>(qbB + (size_t)(n0 + l15) * CO + g4 * 8);
    s8 qf1 = *reinterpret_cast<const s8*>(qbB + (size_t)(n0 + 16 + l15) * CO + g4 * 8);

    char* pbase = plds[w];
    // P layout: [n-row (32)][m (64) * 2B], row pitch 144B (conflict-free).
    // write (h,j): u2 (m=j*16+g4*4 .. +3, n=h*16+l15)
    const int pwr = l15 * 144 + g4 * 8;
    const int pw00 = pwr,              pw01 = pwr + 32,  pw02 = pwr + 64,  pw03 = pwr + 96;
    const int pw10 = pwr + 2304,       pw11 = pw10 + 32, pw12 = pw10 + 64, pw13 = pw10 + 96;
    // read (h,ksl): b128 (m = ksl*32+g4*8 .. +8, n = h*16+l15)
    const int prr = l15 * 144 + g4 * 16;
    const int pr00 = prr,        pr01 = prr + 64;
    const int pr10 = prr + 2304, pr11 = pr10 + 64;

    // incremental global pointers (A = even tiles, B = odd tiles)
    const unsigned short* kpA = kbB + (size_t)l15 * CO + g4 * 8;
    const unsigned short* kpB = kpA + (size_t)64 * CO;
    const unsigned short* vpA = vfr + (size_t)b * 1048576 + ch * 4096 + l * 8;
    const unsigned short* vpB = vpA + 16384;

    s8 kA0, kA1, kA2, kA3, kB0, kB1, kB2, kB3;
    s8 vA[8], vB[8];
    const f4 z = {0.f, 0.f, 0.f, 0.f};

#define LOADKA() do { \
        kA0 = *reinterpret_cast<const s8*>(kpA); \
        kA1 = *reinterpret_cast<const s8*>(kpA + 512); \
        kA2 = *reinterpret_cast<const s8*>(kpA + 1024); \
        kA3 = *reinterpret_cast<const s8*>(kpA + 1536); \
        kpA += 4096; \
    } while (0)
#define LOADKB() do { \
        kB0 = *reinterpret_cast<const s8*>(kpB); \
        kB1 = *reinterpret_cast<const s8*>(kpB + 512); \
        kB2 = *reinterpret_cast<const s8*>(kpB + 1024); \
        kB3 = *reinterpret_cast<const s8*>(kpB + 1536); \
        kpB += 4096; \
    } while (0)
#define LOADVA() do { \
        vA[0] = *reinterpret_cast<const s8*>(vpA); \
        vA[1] = *reinterpret_cast<const s8*>(vpA + 512); \
        vA[2] = *reinterpret_cast<const s8*>(vpA + 1024); \
        vA[3] = *reinterpret_cast<const s8*>(vpA + 1536); \
        vA[4] = *reinterpret_cast<const s8*>(vpA + 2048); \
        vA[5] = *reinterpret_cast<const s8*>(vpA + 2560); \
        vA[6] = *reinterpret_cast<const s8*>(vpA + 3072); \
        vA[7] = *reinterpret_cast<const s8*>(vpA + 3584); \
        vpA += 32768; \
    } while (0)
#define LOADVB() do { \
        vB[0] = *reinterpret_cast<const s8*>(vpB); \
        vB[1] = *reinterpret_cast<const s8*>(vpB + 512); \
        vB[2] = *reinterpret_cast<const s8*>(vpB + 1024); \
        vB[3] = *reinterpret_cast<const s8*>(vpB + 1536); \
        vB[4] = *reinterpret_cast<const s8*>(vpB + 2048); \
        vB[5] = *reinterpret_cast<const s8*>(vpB + 2560); \
        vB[6] = *reinterpret_cast<const s8*>(vpB + 3072); \
        vB[7] = *reinterpret_cast<const s8*>(vpB + 3584); \
        vpB += 32768; \
    } while (0)

    // V frag index: v[ct*2 + ksl]  (A-operand: row c = ct*16+l15, k = m)
#define TILE(K0, K1, K2, K3, V) do { \
        f4 d0 = __builtin_amdgcn_mfma_f32_16x16x32_bf16(K0, qf0, z, 0, 0, 0); \
        f4 d1 = __builtin_amdgcn_mfma_f32_16x16x32_bf16(K1, qf0, z, 0, 0, 0); \
        f4 d2 = __builtin_amdgcn_mfma_f32_16x16x32_bf16(K2, qf0, z, 0, 0, 0); \
        f4 d3 = __builtin_amdgcn_mfma_f32_16x16x32_bf16(K3, qf0, z, 0, 0, 0); \
        *reinterpret_cast<u2*>(pbase + pw00) = (u2){ cvtpk(exp2f(d0[0]), exp2f(d0[1])), cvtpk(exp2f(d0[2]), exp2f(d0[3])) }; \
        *reinterpret_cast<u2*>(pbase + pw01) = (u2){ cvtpk(exp2f(d1[0]), exp2f(d1[1])), cvtpk(exp2f(d1[2]), exp2f(d1[3])) }; \
        *reinterpret_cast<u2*>(pbase + pw02) = (u2){ cvtpk(exp2f(d2[0]), exp2f(d2[1])), cvtpk(exp2f(d2[2]), exp2f(d2[3])) }; \
        *reinterpret_cast<u2*>(pbase + pw03) = (u2){ cvtpk(exp2f(d3[0]), exp2f(d3[1])), cvtpk(exp2f(d3[2]), exp2f(d3[3])) }; \
        d0 = __builtin_amdgcn_mfma_f32_16x16x32_bf16(K0, qf1, z, 0, 0, 0); \
        d1 = __builtin_amdgcn_mfma_f32_16x16x32_bf16(K1, qf1, z, 0, 0, 0); \
        d2 = __builtin_amdgcn_mfma_f32_16x16x32_bf16(K2, qf1, z, 0, 0, 0); \
        d3 = __builtin_amdgcn_mfma_f32_16x16x32_bf16(K3, qf1, z, 0, 0, 0); \
        *reinterpret_cast<u2*>(pbase + pw10) = (u2){ cvtpk(exp2f(d0[0]), exp2f(d0[1])), cvtpk(exp2f(d0[2]), exp2f(d0[3])) }; \
        *reinterpret_cast<u2*>(pbase + pw11) = (u2){ cvtpk(exp2f(d1[0]), exp2f(d1[1])), cvtpk(exp2f(d1[2]), exp2f(d1[3])) }; \
        *reinterpret_cast<u2*>(pbase + pw12) = (u2){ cvtpk(exp2f(d2[0]), exp2f(d2[1])), cvtpk(exp2f(d2[2]), exp2f(d2[3])) }; \
        *reinterpret_cast<u2*>(pbase + pw13) = (u2){ cvtpk(exp2f(d3[0]), exp2f(d3[1])), cvtpk(exp2f(d3[2]), exp2f(d3[3])) }; \
        s8 p00 = *reinterpret_cast<const s8*>(pbase + pr00); \
        s8 p01 = *reinterpret_cast<const s8*>(pbase + pr01); \
        s8 p10 = *reinterpret_cast<const s8*>(pbase + pr10); \
        s8 p11 = *reinterpret_cast<const s8*>(pbase + pr11); \
        __builtin_amdgcn_s_setprio(1); \
        acc00 = __builtin_amdgcn_mfma_f32_16x16x32_bf16(V[0], p00, acc00, 0, 0, 0); \
        acc01 = __builtin_amdgcn_mfma_f32_16x16x32_bf16(V[2], p00, acc01, 0, 0, 0); \
        acc02 = __builtin_amdgcn_mfma_f32_16x16x32_bf16(V[4], p00, acc02, 0, 0, 0); \
        acc03 = __builtin_amdgcn_mfma_f32_16x16x32_bf16(V[6], p00, acc03, 0, 0, 0); \
        acc10 = __builtin_amdgcn_mfma_f32_16x16x32_bf16(V[0], p10, acc10, 0, 0, 0); \
        acc11 = __builtin_amdgcn_mfma_f32_16x16x32_bf16(V[2], p10, acc11, 0, 0, 0); \
        acc12 = __builtin_amdgcn_mfma_f32_16x16x32_bf16(V[4], p10, acc12, 0, 0, 0); \
        acc13 = __builtin_amdgcn_mfma_f32_16x16x32_bf16(V[6], p10, acc13, 0, 0, 0); \
        acc00 = __builtin_amdgcn_mfma_f32_16x16x32_bf16(V[1], p01, acc00, 0, 0, 0); \
        acc01 = __builtin_amdgcn_mfma_f32_16x16x32_bf16(V[3], p01, acc01, 0, 0, 0); \
        acc02 = __builtin_amdgcn_mfma_f32_16x16x32_bf16(V[5], p01, acc02, 0, 0, 0); \
        acc03 = __builtin_amdgcn_mfma_f32_16x16x32_bf16(V[7], p01, acc03, 0, 0, 0); \
        acc10 = __builtin_amdgcn_mfma_f32_16x16x32_bf16(V[1], p11, acc10, 0, 0, 0); \
        acc11 = __builtin_amdgcn_mfma_f32_16x16x32_bf16(V[3], p11, acc11, 0, 0, 0); \
        acc12 = __builtin_amdgcn_mfma_f32_16x16x32_bf16(V[5], p11, acc12, 0, 0, 0); \
        acc13 = __builtin_amdgcn_mfma_f32_16x16x32_bf16(V[7], p11, acc13, 0, 0, 0); \
        __builtin_amdgcn_s_setprio(0); \
    } while (0)

    f4 acc00 = z, acc01 = z, acc02 = z, acc03 = z;
    f4 acc10 = z, acc11 = z, acc12 = z, acc13 = z;

    LOADKA(); LOADVA();      // tile 0
    LOADKB(); LOADVB();      // tile 1

    for (int i = 0; i < 64; i += 2) {
        TILE(kA0, kA1, kA2, kA3, vA);         // tile i
        if (i + 2 < 64) { LOADKA(); LOADVA(); }  // tile i+2
        TILE(kB0, kB1, kB2, kB3, vB);         // tile i+1
        if (i + 3 < 64) { LOADKB(); LOADVB(); }  // tile i+3
    }

#undef LOADKA
#undef LOADKB
#undef LOADVA
#undef LOADVB
#undef TILE

    // D[c][n]: col = l15 (n), row = g4*4 + r (c).  f4 store per (h, ct).
    float* outB = out + (size_t)b * NN * CC;
    #pragma unroll
    for (int h = 0; h < 2; ++h) {
        float* orow = outB + (size_t)(n0 + h * 16 + l15) * CC + c0 + g4 * 4;
        f4 a0 = h ? acc10 : acc00;
        f4 a1 = h ? acc11 : acc01;
        f4 a2 = h ? acc12 : acc02;
        f4 a3 = h ? acc13 : acc03;
        *reinterpret_cast<f4*>(orow)      = a0;
        *reinterpret_cast<f4*>(orow + 16) = a1;
        *reinterpret_cast<f4*>(orow + 32) = a2;
        *reinterpret_cast<f4*>(orow + 48) = a3;
    }
}

extern "C" void kernel_launch(void* const* d_in, const int* in_sizes, int n_in,
                              void* d_out, int out_size, void* d_ws, size_t ws_size,
                              hipStream_t stream)
{
    const float* x  = (const float*)d_in[0];
    const float* Wq = (const float*)d_in[1];
    const float* bq = (const float*)d_in[2];
    const float* Wk = (const float*)d_in[3];
    const float* bk = (const float*)d_in[4];
    const float* Wv = (const float*)d_in[5];
    const float* bv = (const float*)d_in[6];
    float* out = (float*)d_out;

    // ws layout: qb(1MB) | kb(1MB) | vtb(8MB) | vfr(8MB) | Wb(160KB) | fb
    unsigned short* qb  = (unsigned short*)d_ws;
    unsigned short* kb  = qb  + (size_t)NB * NN * CO;
    unsigned short* vtb = kb  + (size_t)NB * NN * CO;
    unsigned short* vfr = vtb + (size_t)NB * CC * NN;
    unsigned short* Wb  = vfr + (size_t)NB * CC * NN;
    float*          fb  = (float*)(Wb + (size_t)MU * CC);

    prepw_kernel<<<dim3(80), dim3(256), 0, stream>>>(Wq, bq, Wk, bk, Wv, bv, Wb, fb);
    projf_kernel<<<dim3(512), dim3(256), 0, stream>>>(x, Wb, fb, qb, kb, vtb);
    colstats_kernel<<<dim3(1024), dim3(256), 0, stream>>>(qb, kb, vtb, vfr);
    attn_kernel<<<dim3(256), dim3(512), 0, stream>>>(qb, kb, vfr, out);
}

// Round 21
// 111.952 us; speedup vs baseline: 1.2901x; 1.2901x over previous
//
#include <hip/hip_runtime.h>
#include <math.h>

#define NB 4
#define CC 256
#define CO 32
#define NN 4096
#define MU 320   // concat projection rows: 32 q + 32 k + 256 v
#define LOG2E 1.44269504088896f

typedef __attribute__((ext_vector_type(4))) float f4;
typedef __attribute__((ext_vector_type(8))) short s8;          // 8 bf16 MFMA frag
typedef __attribute__((ext_vector_type(8))) unsigned short us8;
typedef __attribute__((ext_vector_type(2))) unsigned int u2;
typedef __attribute__((ext_vector_type(4))) unsigned int u4i;

// fp32 -> bf16 (RNE), scalar fallback
__device__ __forceinline__ unsigned short f2bf(float f) {
    unsigned int u = __float_as_uint(f);
    u = (u + 0x7FFFu + ((u >> 16) & 1u)) >> 16;
    return (unsigned short)u;
}
// HW packed convert: dst = {bf16(lo), bf16(hi)}
__device__ __forceinline__ unsigned int cvtpk(float lo, float hi) {
    unsigned int r;
    asm("v_cvt_pk_bf16_f32 %0, %1, %2" : "=v"(r) : "v"(lo), "v"(hi));
    return r;
}
// XOR-swizzled byte offset within a 128B-row LDS tile (verified round 8)
__device__ __forceinline__ int swz128(int row, int colByte) {
    return row * 128 + (colByte ^ ((row & 7) << 4));
}
// Barrier draining only LDS ops; global prefetch loads stay in flight.
#define LDS_BARRIER() asm volatile("s_waitcnt lgkmcnt(0)\n\ts_barrier" ::: "memory")

union s8u4 { s8 s; u4i u; };

// ---------------------------------------------------------------------------
// prepw: grid 80. Wb[320][256] bf16, fb[320] f32.  (passing, unchanged)
// ---------------------------------------------------------------------------
__global__ __launch_bounds__(256) void prepw_kernel(
    const float* __restrict__ Wq, const float* __restrict__ bq,
    const float* __restrict__ Wk, const float* __restrict__ bk,
    const float* __restrict__ Wv, const float* __restrict__ bv,
    unsigned short* __restrict__ Wb, float* __restrict__ fb)
{
    const int t = threadIdx.x;
    #pragma unroll
    for (int i = 0; i < 4; ++i) {
        const int e = blockIdx.x * 1024 + i * 256 + t;
        const int u = e >> 8, c = e & 255;
        float val = (u < 32) ? Wq[u * 256 + c]
                  : (u < 64) ? Wk[(u - 32) * 256 + c]
                             : Wv[(u - 64) * 256 + c];
        Wb[e] = f2bf(val);
    }
    if (blockIdx.x == 0) {
        for (int u = t; u < MU; u += 256)
            fb[u] = (u < 32) ? bq[u] : (u < 64) ? bk[u - 32] : bv[u - 64];
    }
}

// ---------------------------------------------------------------------------
// projf: fused transpose + MFMA projection (passing, unchanged).
// ---------------------------------------------------------------------------
__global__ __launch_bounds__(256) void projf_kernel(
    const float* __restrict__ x, const unsigned short* __restrict__ Wb,
    const float* __restrict__ fb,
    unsigned short* __restrict__ qb, unsigned short* __restrict__ kb,
    unsigned short* __restrict__ vtb)
{
    __shared__ float xl[32][260];

    const int t   = threadIdx.x;
    const int b   = blockIdx.x >> 7;
    const int nbl = blockIdx.x & 127;
    const int n0  = nbl * 32;

    {
        const int nl = t & 7;
        const int c8 = t >> 3;
        #pragma unroll
        for (int pass = 0; pass < 8; ++pass) {
            const int c = c8 + pass * 32;
            f4 xv = *reinterpret_cast<const f4*>(x + ((size_t)(b * CC + c)) * NN + n0 + nl * 4);
            #pragma unroll
            for (int j = 0; j < 4; ++j) xl[nl * 4 + j][c] = xv[j];
        }
    }
    __syncthreads();

    const int w    = t >> 6;
    const int l    = t & 63;
    const int l15  = l & 15;
    const int g4   = l >> 4;
    const int nw   = w & 1;
    const int uw   = w >> 1;
    const int nloc = nw * 16 + l15;
    const int n    = n0 + nloc;

    s8 bfr[8];
    #pragma unroll
    for (int kk = 0; kk < 8; ++kk) {
        f4 a  = *reinterpret_cast<const f4*>(&xl[nloc][kk * 32 + g4 * 8]);
        f4 c2 = *reinterpret_cast<const f4*>(&xl[nloc][kk * 32 + g4 * 8 + 4]);
        s8u4 tmp;
        tmp.u = (u4i){ cvtpk(a[0], a[1]), cvtpk(a[2], a[3]),
                       cvtpk(c2[0], c2[1]), cvtpk(c2[2], c2[3]) };
        bfr[kk] = tmp.s;
    }

    const f4 z = {0.f, 0.f, 0.f, 0.f};
    unsigned short* qrow = qb + ((size_t)(b * NN + n)) * CO;
    unsigned short* krow = kb + ((size_t)(b * NN + n)) * CO;

    #pragma unroll
    for (int i = 0; i < 10; ++i) {
        const int u0 = (uw * 10 + i) * 16;
        f4 acc = z;
        #pragma unroll
        for (int kk = 0; kk < 8; ++kk) {
            s8 af = *reinterpret_cast<const s8*>(Wb + (size_t)(u0 + l15) * CC + kk * 32 + g4 * 8);
            acc = __builtin_amdgcn_mfma_f32_16x16x32_bf16(af, bfr[kk], acc, 0, 0, 0);
        }
        f4 bias4 = *reinterpret_cast<const f4*>(fb + u0 + g4 * 4);
        if (u0 < 32) {
            u2 pw = { cvtpk((acc[0] + bias4[0]) * LOG2E, (acc[1] + bias4[1]) * LOG2E),
                      cvtpk((acc[2] + bias4[2]) * LOG2E, (acc[3] + bias4[3]) * LOG2E) };
            *reinterpret_cast<u2*>(qrow + u0 + g4 * 4) = pw;
        } else if (u0 < 64) {
            u2 pw = { cvtpk(acc[0] + bias4[0], acc[1] + bias4[1]),
                      cvtpk(acc[2] + bias4[2], acc[3] + bias4[3]) };
            *reinterpret_cast<u2*>(krow + (u0 - 32) + g4 * 4) = pw;
        } else {
            const int cbase = u0 - 64 + g4 * 4;
            #pragma unroll
            for (int r = 0; r < 4; ++r)
                vtb[((size_t)(b * CC + cbase + r)) * NN + n] = f2bf(acc[r] + bias4[r]);
        }
    }
}

// ---------------------------------------------------------------------------
// colstats: civ + scaled V in MFMA fragment order (vfr). (passing, unchanged)
// ---------------------------------------------------------------------------
__global__ __launch_bounds__(256) void colstats_kernel(
    const unsigned short* __restrict__ qb, const unsigned short* __restrict__ kb,
    const unsigned short* __restrict__ vtb, unsigned short* __restrict__ vfr)
{
    __shared__ float red[4][16];
    __shared__ float civl[16];

    const int t   = threadIdx.x;
    const int b   = blockIdx.x >> 8;
    const int mb  = blockIdx.x & 255;
    const int l   = t & 63;
    const int w   = t >> 6;
    const int l15 = l & 15;
    const int g4  = l >> 4;
    const int m   = mb * 16 + l15;

    const unsigned short* qbB = qb + (size_t)b * NN * CO;
    s8 kfrag = *reinterpret_cast<const s8*>(kb + ((size_t)b * NN + m) * CO + g4 * 8);

    const f4 z = {0.f, 0.f, 0.f, 0.f};
    float ssum = 0.f;

    const int nbeg = w * 1024, nend = nbeg + 1024;
    for (int n0 = nbeg; n0 < nend; n0 += 32) {
        s8 a0 = *reinterpret_cast<const s8*>(qbB + (size_t)(n0 + l15) * CO + g4 * 8);
        s8 a1 = *reinterpret_cast<const s8*>(qbB + (size_t)(n0 + 16 + l15) * CO + g4 * 8);
        f4 d0 = __builtin_amdgcn_mfma_f32_16x16x32_bf16(a0, kfrag, z, 0, 0, 0);
        f4 d1 = __builtin_amdgcn_mfma_f32_16x16x32_bf16(a1, kfrag, z, 0, 0, 0);
        #pragma unroll
        for (int r = 0; r < 4; ++r) ssum += exp2f(d0[r]) + exp2f(d1[r]);
    }

    ssum += __shfl_xor(ssum, 16);
    ssum += __shfl_xor(ssum, 32);
    if (l < 16) red[w][l15] = ssum;
    __syncthreads();
    if (w == 0 && l < 16)
        civl[l15] = 1.0f / (red[0][l15] + red[1][l15] + red[2][l15] + red[3][l15]);
    __syncthreads();

    const int mt   = mb >> 2;
    const int ksl  = (mb >> 1) & 1;
    const int g4b  = (mb & 1) * 2;
    const int cg   = t >> 4;
    const int l15v = t & 15;
    const unsigned short* vp = vtb + ((size_t)(b * CC + t)) * NN + mb * 16;
    unsigned short* dst = vfr + (size_t)b * 1048576
                        + (((mt * 16 + cg) * 2 + ksl) << 9)
                        + (g4b * 16 + l15v) * 8;
    #pragma unroll
    for (int i = 0; i < 2; ++i) {
        us8 vv = *reinterpret_cast<const us8*>(vp + i * 8);
        u4i o;
        #pragma unroll
        for (int e2 = 0; e2 < 4; ++e2) {
            float f0 = __uint_as_float((unsigned int)vv[2 * e2]     << 16) * civl[i * 8 + 2 * e2];
            float f1 = __uint_as_float((unsigned int)vv[2 * e2 + 1] << 16) * civl[i * 8 + 2 * e2 + 1];
            o[e2] = cvtpk(f0, f1);
        }
        *reinterpret_cast<u4i*>(dst + i * 128) = o;
    }
}

// ---------------------------------------------------------------------------
// attn: 32n x 256c blocks (S computed ONCE per block, V never duplicated).
// grid 512 (XCD-swizzled: each XCD's 64 blocks share one batch's kb+vfr in
// its L2), 512 thr / 8 waves, 2 blocks/CU.
//   S: wave (ng = w>>2: 16 n; mq = w&3: 16 m): 1 swapped S-MFMA, 4 exp2,
//      2 cvtpk, 1 b64 P-write into swizzled plds (8 KB total).
//   PV: wave owns 32n x 32c (c = w*32): 4 pa b128 reads + 4 vfr B-frags in
//      regs + 8 MFMA, acc[2][2].
// 1-deep K/V register prefetch; lgkm-only barriers keep loads in flight.
// ---------------------------------------------------------------------------
__global__ __launch_bounds__(512, 4) void attn_kernel(
    const unsigned short* __restrict__ qb, const unsigned short* __restrict__ kb,
    const unsigned short* __restrict__ vfr, float* __restrict__ out)
{
    __shared__ __align__(16) char plds[2][32 * 128];   // P tile [32n][64m] bf16, swizzled

    const int t   = threadIdx.x;
    const int w   = t >> 6;
    const int l   = t & 63;
    const int l15 = l & 15;
    const int g4  = l >> 4;
    // XCD swizzle: bijective (512 % 8 == 0); 64 consecutive works per XCD
    const int bid  = (blockIdx.x & 7) * 64 + (blockIdx.x >> 3);
    const int b    = bid >> 7;
    const int nblk = bid & 127;
    const int n0   = nblk * 32;
    const int ng   = w >> 2;      // S n-group (16 rows)
    const int mq   = w & 3;       // S m-quarter (16 m)

    const unsigned short* qbB = qb + (size_t)b * NN * CO;
    const unsigned short* kbB = kb + (size_t)b * NN * CO;

    // wave's 16 S-rows (B-operand of swapped MFMA)
    s8 qfrag = *reinterpret_cast<const s8*>(qbB + (size_t)(n0 + ng * 16 + l15) * CO + g4 * 8);

    // ---- loop-invariant LDS byte offsets ----
    const int pwo  = swz128(ng * 16 + l15, mq * 32 + g4 * 8);   // P write (u2)
    const int pr00 = swz128(l15,      g4 * 16);                 // pa[nt0][ksl0]
    const int pr01 = swz128(l15,      64 + g4 * 16);            // pa[nt0][ksl1]
    const int pr10 = swz128(16 + l15, g4 * 16);                 // pa[nt1][ksl0]
    const int pr11 = swz128(16 + l15, 64 + g4 * 16);            // pa[nt1][ksl1]

    // ---- incremental global pointers ----
    const unsigned short* kp = kbB + (size_t)(mq * 16 + l15) * CO + g4 * 8;
    // vfr: chunk (mt, cg = w*2 + ct, ksl) at ((mt*16+cg)*2+ksl)*512 + lane*8
    const unsigned short* vp = vfr + (size_t)b * 1048576 + w * 2048 + l * 8;

    s8 kreg;
    s8 v0, v1, v2, v3;       // [ct*2 + ksl]
    const f4 z = {0.f, 0.f, 0.f, 0.f};
    f4 acc00 = z, acc01 = z, acc10 = z, acc11 = z;   // [nt][ct]

#define LOADK() do { kreg = *reinterpret_cast<const s8*>(kp); kp += 2048; } while (0)
#define LOADV() do { \
        v0 = *reinterpret_cast<const s8*>(vp); \
        v1 = *reinterpret_cast<const s8*>(vp + 512); \
        v2 = *reinterpret_cast<const s8*>(vp + 1024); \
        v3 = *reinterpret_cast<const s8*>(vp + 1536); \
        vp += 16384; \
    } while (0)

#define STAGE(BUF, KR) do { \
        f4 d = __builtin_amdgcn_mfma_f32_16x16x32_bf16(KR, qfrag, z, 0, 0, 0); \
        u2 pw = { cvtpk(exp2f(d[0]), exp2f(d[1])), cvtpk(exp2f(d[2]), exp2f(d[3])) }; \
        *reinterpret_cast<u2*>(plds[BUF] + pwo) = pw; \
    } while (0)

#define PVSTEP(BUF) do { \
        s8 pa00 = *reinterpret_cast<const s8*>(plds[BUF] + pr00); \
        s8 pa01 = *reinterpret_cast<const s8*>(plds[BUF] + pr01); \
        s8 pa10 = *reinterpret_cast<const s8*>(plds[BUF] + pr10); \
        s8 pa11 = *reinterpret_cast<const s8*>(plds[BUF] + pr11); \
        __builtin_amdgcn_s_setprio(1); \
        acc00 = __builtin_amdgcn_mfma_f32_16x16x32_bf16(pa00, v0, acc00, 0, 0, 0); \
        acc01 = __builtin_amdgcn_mfma_f32_16x16x32_bf16(pa00, v2, acc01, 0, 0, 0); \
        acc10 = __builtin_amdgcn_mfma_f32_16x16x32_bf16(pa10, v0, acc10, 0, 0, 0); \
        acc11 = __builtin_amdgcn_mfma_f32_16x16x32_bf16(pa10, v2, acc11, 0, 0, 0); \
        acc00 = __builtin_amdgcn_mfma_f32_16x16x32_bf16(pa01, v1, acc00, 0, 0, 0); \
        acc01 = __builtin_amdgcn_mfma_f32_16x16x32_bf16(pa01, v3, acc01, 0, 0, 0); \
        acc10 = __builtin_amdgcn_mfma_f32_16x16x32_bf16(pa11, v1, acc10, 0, 0, 0); \
        acc11 = __builtin_amdgcn_mfma_f32_16x16x32_bf16(pa11, v3, acc11, 0, 0, 0); \
        __builtin_amdgcn_s_setprio(0); \
    } while (0)

    // prologue: K0 (temp), K1 -> kreg, V0 -> vregs, stage P0
    s8 k0 = *reinterpret_cast<const s8*>(kp); kp += 2048;   // K(0)
    LOADK();                                                // kreg = K(1)
    LOADV();                                                // V(0)
    STAGE(0, k0);                                           // P(0)
    LDS_BARRIER();

    for (int i = 0; i < 64; i += 2) {
        STAGE(1, kreg);                 // P(i+1)
        if (i < 62) LOADK();            // K(i+2)
        PVSTEP(0);                      // tile i   (uses V(i))
        if (i < 63) LOADV();            // V(i+1)
        LDS_BARRIER();

        if (i + 1 < 63) STAGE(0, kreg); // P(i+2)
        if (i + 1 < 62) LOADK();        // K(i+3)
        PVSTEP(1);                      // tile i+1 (uses V(i+1))
        if (i + 1 < 63) LOADV();        // V(i+2)
        LDS_BARRIER();
    }

#undef LOADK
#undef LOADV
#undef STAGE
#undef PVSTEP

    // D layout: col = lane&15 -> c, row = g4*4 + r -> n
    float* ob = out + (size_t)b * NN * CC;
    const int cw = w * 32 + l15;
    #pragma unroll
    for (int r = 0; r < 4; ++r) {
        const size_t row0 = (size_t)(n0 + g4 * 4 + r) * CC;
        const size_t row1 = (size_t)(n0 + 16 + g4 * 4 + r) * CC;
        ob[row0 + cw]      = acc00[r];
        ob[row0 + cw + 16] = acc01[r];
        ob[row1 + cw]      = acc10[r];
        ob[row1 + cw + 16] = acc11[r];
    }
}

extern "C" void kernel_launch(void* const* d_in, const int* in_sizes, int n_in,
                              void* d_out, int out_size, void* d_ws, size_t ws_size,
                              hipStream_t stream)
{
    const float* x  = (const float*)d_in[0];
    const float* Wq = (const float*)d_in[1];
    const float* bq = (const float*)d_in[2];
    const float* Wk = (const float*)d_in[3];
    const float* bk = (const float*)d_in[4];
    const float* Wv = (const float*)d_in[5];
    const float* bv = (const float*)d_in[6];
    float* out = (float*)d_out;

    // ws layout: qb(1MB) | kb(1MB) | vtb(8MB) | vfr(8MB) | Wb(160KB) | fb
    unsigned short* qb  = (unsigned short*)d_ws;
    unsigned short* kb  = qb  + (size_t)NB * NN * CO;
    unsigned short* vtb = kb  + (size_t)NB * NN * CO;
    unsigned short* vfr = vtb + (size_t)NB * CC * NN;
    unsigned short* Wb  = vfr + (size_t)NB * CC * NN;
    float*          fb  = (float*)(Wb + (size_t)MU * CC);

    prepw_kernel<<<dim3(80), dim3(256), 0, stream>>>(Wq, bq, Wk, bk, Wv, bv, Wb, fb);
    projf_kernel<<<dim3(512), dim3(256), 0, stream>>>(x, Wb, fb, qb, kb, vtb);
    colstats_kernel<<<dim3(1024), dim3(256), 0, stream>>>(qb, kb, vtb, vfr);
    attn_kernel<<<dim3(512), dim3(512), 0, stream>>>(qb, kb, vfr, out);
}

// Round 22
// 111.668 us; speedup vs baseline: 1.2934x; 1.0025x over previous
//
#include <hip/hip_runtime.h>
#include <math.h>

#define NB 4
#define CC 256
#define CO 32
#define NN 4096
#define MU 320   // concat projection rows: 32 q + 32 k + 256 v
#define LOG2E 1.44269504088896f

typedef __attribute__((ext_vector_type(4))) float f4;
typedef __attribute__((ext_vector_type(8))) short s8;          // 8 bf16 MFMA frag
typedef __attribute__((ext_vector_type(8))) unsigned short us8;
typedef __attribute__((ext_vector_type(2))) unsigned int u2;
typedef __attribute__((ext_vector_type(4))) unsigned int u4i;

// fp32 -> bf16 (RNE), scalar fallback
__device__ __forceinline__ unsigned short f2bf(float f) {
    unsigned int u = __float_as_uint(f);
    u = (u + 0x7FFFu + ((u >> 16) & 1u)) >> 16;
    return (unsigned short)u;
}
// HW packed convert: dst = {bf16(lo), bf16(hi)}
__device__ __forceinline__ unsigned int cvtpk(float lo, float hi) {
    unsigned int r;
    asm("v_cvt_pk_bf16_f32 %0, %1, %2" : "=v"(r) : "v"(lo), "v"(hi));
    return r;
}
// XOR-swizzled byte offset within a 128B-row LDS tile (verified round 8)
__device__ __forceinline__ int swz128(int row, int colByte) {
    return row * 128 + (colByte ^ ((row & 7) << 4));
}
// Barrier draining only LDS ops; global prefetch loads stay in flight.
#define LDS_BARRIER() asm volatile("s_waitcnt lgkmcnt(0)\n\ts_barrier" ::: "memory")

union s8u4 { s8 s; u4i u; };

// ---------------------------------------------------------------------------
// prepw: grid 80. Wb[320][256] bf16, fb[320] f32.  (passing, unchanged)
// ---------------------------------------------------------------------------
__global__ __launch_bounds__(256) void prepw_kernel(
    const float* __restrict__ Wq, const float* __restrict__ bq,
    const float* __restrict__ Wk, const float* __restrict__ bk,
    const float* __restrict__ Wv, const float* __restrict__ bv,
    unsigned short* __restrict__ Wb, float* __restrict__ fb)
{
    const int t = threadIdx.x;
    #pragma unroll
    for (int i = 0; i < 4; ++i) {
        const int e = blockIdx.x * 1024 + i * 256 + t;
        const int u = e >> 8, c = e & 255;
        float val = (u < 32) ? Wq[u * 256 + c]
                  : (u < 64) ? Wk[(u - 32) * 256 + c]
                             : Wv[(u - 64) * 256 + c];
        Wb[e] = f2bf(val);
    }
    if (blockIdx.x == 0) {
        for (int u = t; u < MU; u += 256)
            fb[u] = (u < 32) ? bq[u] : (u < 64) ? bk[u - 32] : bv[u - 64];
    }
}

// ---------------------------------------------------------------------------
// projf: fused transpose + MFMA projection (passing, unchanged).
// ---------------------------------------------------------------------------
__global__ __launch_bounds__(256) void projf_kernel(
    const float* __restrict__ x, const unsigned short* __restrict__ Wb,
    const float* __restrict__ fb,
    unsigned short* __restrict__ qb, unsigned short* __restrict__ kb,
    unsigned short* __restrict__ vtb)
{
    __shared__ float xl[32][260];

    const int t   = threadIdx.x;
    const int b   = blockIdx.x >> 7;
    const int nbl = blockIdx.x & 127;
    const int n0  = nbl * 32;

    {
        const int nl = t & 7;
        const int c8 = t >> 3;
        #pragma unroll
        for (int pass = 0; pass < 8; ++pass) {
            const int c = c8 + pass * 32;
            f4 xv = *reinterpret_cast<const f4*>(x + ((size_t)(b * CC + c)) * NN + n0 + nl * 4);
            #pragma unroll
            for (int j = 0; j < 4; ++j) xl[nl * 4 + j][c] = xv[j];
        }
    }
    __syncthreads();

    const int w    = t >> 6;
    const int l    = t & 63;
    const int l15  = l & 15;
    const int g4   = l >> 4;
    const int nw   = w & 1;
    const int uw   = w >> 1;
    const int nloc = nw * 16 + l15;
    const int n    = n0 + nloc;

    s8 bfr[8];
    #pragma unroll
    for (int kk = 0; kk < 8; ++kk) {
        f4 a  = *reinterpret_cast<const f4*>(&xl[nloc][kk * 32 + g4 * 8]);
        f4 c2 = *reinterpret_cast<const f4*>(&xl[nloc][kk * 32 + g4 * 8 + 4]);
        s8u4 tmp;
        tmp.u = (u4i){ cvtpk(a[0], a[1]), cvtpk(a[2], a[3]),
                       cvtpk(c2[0], c2[1]), cvtpk(c2[2], c2[3]) };
        bfr[kk] = tmp.s;
    }

    const f4 z = {0.f, 0.f, 0.f, 0.f};
    unsigned short* qrow = qb + ((size_t)(b * NN + n)) * CO;
    unsigned short* krow = kb + ((size_t)(b * NN + n)) * CO;

    #pragma unroll
    for (int i = 0; i < 10; ++i) {
        const int u0 = (uw * 10 + i) * 16;
        f4 acc = z;
        #pragma unroll
        for (int kk = 0; kk < 8; ++kk) {
            s8 af = *reinterpret_cast<const s8*>(Wb + (size_t)(u0 + l15) * CC + kk * 32 + g4 * 8);
            acc = __builtin_amdgcn_mfma_f32_16x16x32_bf16(af, bfr[kk], acc, 0, 0, 0);
        }
        f4 bias4 = *reinterpret_cast<const f4*>(fb + u0 + g4 * 4);
        if (u0 < 32) {
            u2 pw = { cvtpk((acc[0] + bias4[0]) * LOG2E, (acc[1] + bias4[1]) * LOG2E),
                      cvtpk((acc[2] + bias4[2]) * LOG2E, (acc[3] + bias4[3]) * LOG2E) };
            *reinterpret_cast<u2*>(qrow + u0 + g4 * 4) = pw;
        } else if (u0 < 64) {
            u2 pw = { cvtpk(acc[0] + bias4[0], acc[1] + bias4[1]),
                      cvtpk(acc[2] + bias4[2], acc[3] + bias4[3]) };
            *reinterpret_cast<u2*>(krow + (u0 - 32) + g4 * 4) = pw;
        } else {
            const int cbase = u0 - 64 + g4 * 4;
            #pragma unroll
            for (int r = 0; r < 4; ++r)
                vtb[((size_t)(b * CC + cbase + r)) * NN + n] = f2bf(acc[r] + bias4[r]);
        }
    }
}

// ---------------------------------------------------------------------------
// colstats: civ + scaled V in MFMA fragment order (vfr). (passing, unchanged)
// ---------------------------------------------------------------------------
__global__ __launch_bounds__(256) void colstats_kernel(
    const unsigned short* __restrict__ qb, const unsigned short* __restrict__ kb,
    const unsigned short* __restrict__ vtb, unsigned short* __restrict__ vfr)
{
    __shared__ float red[4][16];
    __shared__ float civl[16];

    const int t   = threadIdx.x;
    const int b   = blockIdx.x >> 8;
    const int mb  = blockIdx.x & 255;
    const int l   = t & 63;
    const int w   = t >> 6;
    const int l15 = l & 15;
    const int g4  = l >> 4;
    const int m   = mb * 16 + l15;

    const unsigned short* qbB = qb + (size_t)b * NN * CO;
    s8 kfrag = *reinterpret_cast<const s8*>(kb + ((size_t)b * NN + m) * CO + g4 * 8);

    const f4 z = {0.f, 0.f, 0.f, 0.f};
    float ssum = 0.f;

    const int nbeg = w * 1024, nend = nbeg + 1024;
    for (int n0 = nbeg; n0 < nend; n0 += 32) {
        s8 a0 = *reinterpret_cast<const s8*>(qbB + (size_t)(n0 + l15) * CO + g4 * 8);
        s8 a1 = *reinterpret_cast<const s8*>(qbB + (size_t)(n0 + 16 + l15) * CO + g4 * 8);
        f4 d0 = __builtin_amdgcn_mfma_f32_16x16x32_bf16(a0, kfrag, z, 0, 0, 0);
        f4 d1 = __builtin_amdgcn_mfma_f32_16x16x32_bf16(a1, kfrag, z, 0, 0, 0);
        #pragma unroll
        for (int r = 0; r < 4; ++r) ssum += exp2f(d0[r]) + exp2f(d1[r]);
    }

    ssum += __shfl_xor(ssum, 16);
    ssum += __shfl_xor(ssum, 32);
    if (l < 16) red[w][l15] = ssum;
    __syncthreads();
    if (w == 0 && l < 16)
        civl[l15] = 1.0f / (red[0][l15] + red[1][l15] + red[2][l15] + red[3][l15]);
    __syncthreads();

    const int mt   = mb >> 2;
    const int ksl  = (mb >> 1) & 1;
    const int g4b  = (mb & 1) * 2;
    const int cg   = t >> 4;
    const int l15v = t & 15;
    const unsigned short* vp = vtb + ((size_t)(b * CC + t)) * NN + mb * 16;
    unsigned short* dst = vfr + (size_t)b * 1048576
                        + (((mt * 16 + cg) * 2 + ksl) << 9)
                        + (g4b * 16 + l15v) * 8;
    #pragma unroll
    for (int i = 0; i < 2; ++i) {
        us8 vv = *reinterpret_cast<const us8*>(vp + i * 8);
        u4i o;
        #pragma unroll
        for (int e2 = 0; e2 < 4; ++e2) {
            float f0 = __uint_as_float((unsigned int)vv[2 * e2]     << 16) * civl[i * 8 + 2 * e2];
            float f1 = __uint_as_float((unsigned int)vv[2 * e2 + 1] << 16) * civl[i * 8 + 2 * e2 + 1];
            o[e2] = cvtpk(f0, f1);
        }
        *reinterpret_cast<u4i*>(dst + i * 128) = o;
    }
}

// ---------------------------------------------------------------------------
// attn: round-21 structure (32n x 256c, S once, V never duplicated, XCD
// swizzle) with ONE change: FOUR P buffers, 2 tiles per barrier phase
// (barrier count halved).  Unroll-by-4 loop, literal buffer indices, no tail
// guards (overrun loads stay inside d_ws; overrun stages write unread bufs).
// ---------------------------------------------------------------------------
__global__ __launch_bounds__(512, 4) void attn_kernel(
    const unsigned short* __restrict__ qb, const unsigned short* __restrict__ kb,
    const unsigned short* __restrict__ vfr, float* __restrict__ out)
{
    __shared__ __align__(16) char plds[4][32 * 128];   // P tiles, swizzled (16 KB)

    const int t   = threadIdx.x;
    const int w   = t >> 6;
    const int l   = t & 63;
    const int l15 = l & 15;
    const int g4  = l >> 4;
    // XCD swizzle: bijective (512 % 8 == 0); 64 consecutive works per XCD
    const int bid  = (blockIdx.x & 7) * 64 + (blockIdx.x >> 3);
    const int b    = bid >> 7;
    const int nblk = bid & 127;
    const int n0   = nblk * 32;
    const int ng   = w >> 2;      // S n-group (16 rows)
    const int mq   = w & 3;       // S m-quarter (16 m)

    const unsigned short* qbB = qb + (size_t)b * NN * CO;
    const unsigned short* kbB = kb + (size_t)b * NN * CO;

    // wave's 16 S-rows (B-operand of swapped MFMA)
    s8 qfrag = *reinterpret_cast<const s8*>(qbB + (size_t)(n0 + ng * 16 + l15) * CO + g4 * 8);

    // ---- loop-invariant LDS byte offsets ----
    const int pwo  = swz128(ng * 16 + l15, mq * 32 + g4 * 8);   // P write (u2)
    const int pr00 = swz128(l15,      g4 * 16);                 // pa[nt0][ksl0]
    const int pr01 = swz128(l15,      64 + g4 * 16);            // pa[nt0][ksl1]
    const int pr10 = swz128(16 + l15, g4 * 16);                 // pa[nt1][ksl0]
    const int pr11 = swz128(16 + l15, 64 + g4 * 16);            // pa[nt1][ksl1]

    // ---- incremental global pointers ----
    const unsigned short* kp = kbB + (size_t)(mq * 16 + l15) * CO + g4 * 8;
    const unsigned short* vp = vfr + (size_t)b * 1048576 + w * 2048 + l * 8;

    const f4 z = {0.f, 0.f, 0.f, 0.f};
    f4 acc00 = z, acc01 = z, acc10 = z, acc11 = z;   // [nt][ct]

    s8 kA, kB, kC, kD;                  // 4-deep K prefetch
    s8 vA0, vA1, vA2, vA3;              // V set A (even tiles)
    s8 vB0, vB1, vB2, vB3;              // V set B (odd tiles)

#define LOADK(KR) do { KR = *reinterpret_cast<const s8*>(kp); kp += 2048; } while (0)
#define LOADVA() do { \
        vA0 = *reinterpret_cast<const s8*>(vp); \
        vA1 = *reinterpret_cast<const s8*>(vp + 512); \
        vA2 = *reinterpret_cast<const s8*>(vp + 1024); \
        vA3 = *reinterpret_cast<const s8*>(vp + 1536); \
        vp += 16384; \
    } while (0)
#define LOADVB() do { \
        vB0 = *reinterpret_cast<const s8*>(vp); \
        vB1 = *reinterpret_cast<const s8*>(vp + 512); \
        vB2 = *reinterpret_cast<const s8*>(vp + 1024); \
        vB3 = *reinterpret_cast<const s8*>(vp + 1536); \
        vp += 16384; \
    } while (0)

#define STAGE(BUF, KR) do { \
        f4 d = __builtin_amdgcn_mfma_f32_16x16x32_bf16(KR, qfrag, z, 0, 0, 0); \
        u2 pw = { cvtpk(exp2f(d[0]), exp2f(d[1])), cvtpk(exp2f(d[2]), exp2f(d[3])) }; \
        *reinterpret_cast<u2*>(plds[BUF] + pwo) = pw; \
    } while (0)

#define PVSTEP(BUF, V0, V1, V2, V3) do { \
        s8 pa00 = *reinterpret_cast<const s8*>(plds[BUF] + pr00); \
        s8 pa01 = *reinterpret_cast<const s8*>(plds[BUF] + pr01); \
        s8 pa10 = *reinterpret_cast<const s8*>(plds[BUF] + pr10); \
        s8 pa11 = *reinterpret_cast<const s8*>(plds[BUF] + pr11); \
        __builtin_amdgcn_s_setprio(1); \
        acc00 = __builtin_amdgcn_mfma_f32_16x16x32_bf16(pa00, V0, acc00, 0, 0, 0); \
        acc01 = __builtin_amdgcn_mfma_f32_16x16x32_bf16(pa00, V2, acc01, 0, 0, 0); \
        acc10 = __builtin_amdgcn_mfma_f32_16x16x32_bf16(pa10, V0, acc10, 0, 0, 0); \
        acc11 = __builtin_amdgcn_mfma_f32_16x16x32_bf16(pa10, V2, acc11, 0, 0, 0); \
        acc00 = __builtin_amdgcn_mfma_f32_16x16x32_bf16(pa01, V1, acc00, 0, 0, 0); \
        acc01 = __builtin_amdgcn_mfma_f32_16x16x32_bf16(pa01, V3, acc01, 0, 0, 0); \
        acc10 = __builtin_amdgcn_mfma_f32_16x16x32_bf16(pa11, V1, acc10, 0, 0, 0); \
        acc11 = __builtin_amdgcn_mfma_f32_16x16x32_bf16(pa11, V3, acc11, 0, 0, 0); \
        __builtin_amdgcn_s_setprio(0); \
    } while (0)

    // prologue: K0..K5, V0,V1 in flight; stage P0,P1; barrier.
    s8 k0, k1;
    LOADK(k0); LOADK(k1);                // K0, K1
    LOADK(kA); LOADK(kB);                // K2, K3
    LOADK(kC); LOADK(kD);                // K4, K5
    LOADVA();                            // V0
    LOADVB();                            // V1
    STAGE(0, k0);                        // P0
    STAGE(1, k1);                        // P1
    LDS_BARRIER();

    for (int i = 0; i < 64; i += 4) {
        // phase A: stage P(i+2),P(i+3); PV tiles i, i+1
        STAGE(2, kA); LOADK(kA);         // kA <- K(i+6)
        STAGE(3, kB); LOADK(kB);         // kB <- K(i+7)
        PVSTEP(0, vA0, vA1, vA2, vA3);   // tile i     (V(i))
        LOADVA();                        // vA <- V(i+2)
        PVSTEP(1, vB0, vB1, vB2, vB3);   // tile i+1   (V(i+1))
        LOADVB();                        // vB <- V(i+3)
        LDS_BARRIER();

        // phase B: stage P(i+4),P(i+5); PV tiles i+2, i+3
        STAGE(0, kC); LOADK(kC);         // kC <- K(i+8)
        STAGE(1, kD); LOADK(kD);         // kD <- K(i+9)
        PVSTEP(2, vA0, vA1, vA2, vA3);   // tile i+2   (V(i+2))
        LOADVA();                        // vA <- V(i+4)
        PVSTEP(3, vB0, vB1, vB2, vB3);   // tile i+3   (V(i+3))
        LOADVB();                        // vB <- V(i+5)
        LDS_BARRIER();
    }

#undef LOADK
#undef LOADVA
#undef LOADVB
#undef STAGE
#undef PVSTEP

    // D layout: col = lane&15 -> c, row = g4*4 + r -> n
    float* ob = out + (size_t)b * NN * CC;
    const int cw = w * 32 + l15;
    #pragma unroll
    for (int r = 0; r < 4; ++r) {
        const size_t row0 = (size_t)(n0 + g4 * 4 + r) * CC;
        const size_t row1 = (size_t)(n0 + 16 + g4 * 4 + r) * CC;
        ob[row0 + cw]      = acc00[r];
        ob[row0 + cw + 16] = acc01[r];
        ob[row1 + cw]      = acc10[r];
        ob[row1 + cw + 16] = acc11[r];
    }
}

extern "C" void kernel_launch(void* const* d_in, const int* in_sizes, int n_in,
                              void* d_out, int out_size, void* d_ws, size_t ws_size,
                              hipStream_t stream)
{
    const float* x  = (const float*)d_in[0];
    const float* Wq = (const float*)d_in[1];
    const float* bq = (const float*)d_in[2];
    const float* Wk = (const float*)d_in[3];
    const float* bk = (const float*)d_in[4];
    const float* Wv = (const float*)d_in[5];
    const float* bv = (const float*)d_in[6];
    float* out = (float*)d_out;

    // ws layout: qb(1MB) | kb(1MB) | vtb(8MB) | vfr(8MB) | Wb(160KB) | fb
    unsigned short* qb  = (unsigned short*)d_ws;
    unsigned short* kb  = qb  + (size_t)NB * NN * CO;
    unsigned short* vtb = kb  + (size_t)NB * NN * CO;
    unsigned short* vfr = vtb + (size_t)NB * CC * NN;
    unsigned short* Wb  = vfr + (size_t)NB * CC * NN;
    float*          fb  = (float*)(Wb + (size_t)MU * CC);

    prepw_kernel<<<dim3(80), dim3(256), 0, stream>>>(Wq, bq, Wk, bk, Wv, bv, Wb, fb);
    projf_kernel<<<dim3(512), dim3(256), 0, stream>>>(x, Wb, fb, qb, kb, vtb);
    colstats_kernel<<<dim3(1024), dim3(256), 0, stream>>>(qb, kb, vtb, vfr);
    attn_kernel<<<dim3(512), dim3(512), 0, stream>>>(qb, kb, vfr, out);
}